// Round 4
// baseline (277.083 us; speedup 1.0000x reference)
//
#include <hip/hip_runtime.h>
#include <hip/hip_bf16.h>
#include <stdint.h>

typedef __bf16 bf16x4 __attribute__((ext_vector_type(4)));
typedef __bf16 bf16x8 __attribute__((ext_vector_type(8)));
typedef float  f32x4  __attribute__((ext_vector_type(4)));

#define LOG2E 1.44269504088896f

__device__ __forceinline__ void gl2lds16(const __bf16* g, __bf16* l) {
    __builtin_amdgcn_global_load_lds(
        (const __attribute__((address_space(1))) void*)g,
        (__attribute__((address_space(3))) void*)l, 16, 0, 0);
}

// ---------------- elementwise fp32 -> bf16 (grid exactly covers n, n % 2048 == 0) -------------
__global__ __launch_bounds__(256) void cvt_f32_bf16(const float* __restrict__ in,
                                                    __bf16* __restrict__ out) {
    size_t i = ((size_t)blockIdx.x * 256 + threadIdx.x) * 8;
    float4 a = ((const float4*)(in + i))[0];
    float4 b = ((const float4*)(in + i))[1];
    bf16x8 v;
    v[0] = (__bf16)a.x; v[1] = (__bf16)a.y; v[2] = (__bf16)a.z; v[3] = (__bf16)a.w;
    v[4] = (__bf16)b.x; v[5] = (__bf16)b.y; v[6] = (__bf16)b.z; v[7] = (__bf16)b.w;
    *(bf16x8*)(out + i) = v;
}

// ---------------- all-bf16 GEMM, m97 structure, 128x128 tile ---------------------------------
// v2: (a) MFMA operands swapped (bf first) so D's (lq,reg) axis = N -> each thread holds 4
//     CONSECUTIVE columns at one row -> 16 vector stores (b64 bf16 / b128 f32) replace 64
//     scalar stores; 4 lanes per row give 64B-contiguous write granularity.
//     (b) bijective XCD swizzle on the flattened block id (grid % 8 == 0) for A-panel L2 reuse.
template<typename TC>
__global__ __launch_bounds__(256) void gemm_bt_bf16(
    const __bf16* __restrict__ A, const __bf16* __restrict__ B,
    const float* __restrict__ bias, TC* __restrict__ C,
    int M, int N, int K, int lda, int ldb, int ldc)
{
    __shared__ __bf16 As[128][32];
    __shared__ __bf16 Bs[128][32];
    const int tid = threadIdx.x;
    const int wave = tid >> 6, lane = tid & 63;
    const int lr = lane & 15, lq = lane >> 4;

    // XCD-aware bijective swizzle: consecutive swizzled ids share an XCD -> A-panel L2 reuse
    const unsigned gx = gridDim.x;
    const unsigned lin = blockIdx.y * gx + blockIdx.x;
    const unsigned cpx = (gx * gridDim.y) >> 3;
    const unsigned wg = (lin & 7) * cpx + (lin >> 3);
    const int m0 = (int)(wg / gx) * 128, n0 = (int)(wg % gx) * 128;
    const int wm = (wave >> 1) * 64, wn = (wave & 1) * 64;

    f32x4 acc[4][4] = {};

    const int sr = lane >> 2;
    const int sc = (lane & 3) * 8;
    const __bf16* ag[2]; const __bf16* bg[2];
    __bf16* alds[2]; __bf16* blds[2];
    for (int t = 0; t < 2; ++t) {
        int chunk = wave * 2 + t;
        ag[t] = A + (size_t)(m0 + chunk * 16 + sr) * lda + sc;
        bg[t] = B + (size_t)(n0 + chunk * 16 + sr) * ldb + sc;
        alds[t] = &As[0][0] + chunk * 512;
        blds[t] = &Bs[0][0] + chunk * 512;
    }

    for (int k0 = 0; k0 < K; k0 += 32) {
        __syncthreads();
        gl2lds16(ag[0] + k0, alds[0]);
        gl2lds16(ag[1] + k0, alds[1]);
        gl2lds16(bg[0] + k0, blds[0]);
        gl2lds16(bg[1] + k0, blds[1]);
        __syncthreads();
        bf16x8 af[4], bf[4];
        for (int i = 0; i < 4; ++i) af[i] = *(const bf16x8*)&As[wm + i * 16 + lr][lq * 8];
        for (int j = 0; j < 4; ++j) bf[j] = *(const bf16x8*)&Bs[wn + j * 16 + lr][lq * 8];
        for (int i = 0; i < 4; ++i)
            for (int j = 0; j < 4; ++j)
                acc[i][j] = __builtin_amdgcn_mfma_f32_16x16x32_bf16(bf[j], af[i], acc[i][j], 0, 0, 0);
    }

    // epilogue: D row axis (lq,reg) = N (4 consecutive cols), D col axis (lr) = M row
    float4 bv4[4] = {{0.f,0.f,0.f,0.f},{0.f,0.f,0.f,0.f},{0.f,0.f,0.f,0.f},{0.f,0.f,0.f,0.f}};
    if (bias)
        for (int j = 0; j < 4; ++j)
            bv4[j] = *(const float4*)&bias[n0 + wn + j * 16 + lq * 4];
    for (int i = 0; i < 4; ++i) {
        const int row = m0 + wm + i * 16 + lr;
        for (int j = 0; j < 4; ++j) {
            const int col = n0 + wn + j * 16 + lq * 4;
            if constexpr (sizeof(TC) == 2) {
                bf16x4 ob;
                ob[0] = (__bf16)(acc[i][j][0] + bv4[j].x);
                ob[1] = (__bf16)(acc[i][j][1] + bv4[j].y);
                ob[2] = (__bf16)(acc[i][j][2] + bv4[j].z);
                ob[3] = (__bf16)(acc[i][j][3] + bv4[j].w);
                *(bf16x4*)&C[(size_t)row * ldc + col] = ob;
            } else {
                float4 ov;
                ov.x = acc[i][j][0] + bv4[j].x;
                ov.y = acc[i][j][1] + bv4[j].y;
                ov.z = acc[i][j][2] + bv4[j].z;
                ov.w = acc[i][j][3] + bv4[j].w;
                *(float4*)&C[(size_t)row * ldc + col] = ov;
            }
        }
    }
}

// ---------------- fallback GEMM: fp32 ingest, stage16 cvt ------------------------------------
__device__ __forceinline__ void stage16(const float* __restrict__ g, __bf16* l) {
    float4 a = ((const float4*)g)[0];
    float4 b = ((const float4*)g)[1];
    float4 c = ((const float4*)g)[2];
    float4 d = ((const float4*)g)[3];
    bf16x8 lo, hi;
    lo[0] = (__bf16)a.x; lo[1] = (__bf16)a.y; lo[2] = (__bf16)a.z; lo[3] = (__bf16)a.w;
    lo[4] = (__bf16)b.x; lo[5] = (__bf16)b.y; lo[6] = (__bf16)b.z; lo[7] = (__bf16)b.w;
    hi[0] = (__bf16)c.x; hi[1] = (__bf16)c.y; hi[2] = (__bf16)c.z; hi[3] = (__bf16)c.w;
    hi[4] = (__bf16)d.x; hi[5] = (__bf16)d.y; hi[6] = (__bf16)d.z; hi[7] = (__bf16)d.w;
    ((bf16x8*)l)[0] = lo;
    ((bf16x8*)l)[1] = hi;
}
__device__ __forceinline__ void stage16(const __bf16* __restrict__ g, __bf16* l) {
    ((bf16x8*)l)[0] = ((const bf16x8*)g)[0];
    ((bf16x8*)l)[1] = ((const bf16x8*)g)[1];
}

template<typename TA, typename TB, typename TC>
__global__ __launch_bounds__(256) void gemm_bt(
    const TA* __restrict__ A, const TB* __restrict__ B,
    const float* __restrict__ bias, TC* __restrict__ C,
    int M, int N, int K, int lda, int ldb, int ldc)
{
    __shared__ __bf16 As[128][40];
    __shared__ __bf16 Bs[128][40];
    const int tid = threadIdx.x;
    const int wave = tid >> 6, lane = tid & 63;
    const int lr = lane & 15, lq = lane >> 4;
    const unsigned gx = gridDim.x;
    const unsigned lin = blockIdx.y * gx + blockIdx.x;
    const unsigned cpx = (gx * gridDim.y) >> 3;
    const unsigned wg = (lin & 7) * cpx + (lin >> 3);
    const int m0 = (int)(wg / gx) * 128, n0 = (int)(wg % gx) * 128;
    const int wm = (wave >> 1) * 64, wn = (wave & 1) * 64;
    const int srow = tid >> 1, scol = (tid & 1) * 16;

    f32x4 acc[4][4] = {};
    const TA* agp = A + (size_t)(m0 + srow) * lda + scol;
    const TB* bgp = B + (size_t)(n0 + srow) * ldb + scol;

    for (int k0 = 0; k0 < K; k0 += 32) {
        __syncthreads();
        stage16(agp + k0, &As[srow][scol]);
        stage16(bgp + k0, &Bs[srow][scol]);
        __syncthreads();
        bf16x8 af[4], bf[4];
        for (int i = 0; i < 4; ++i) af[i] = *(const bf16x8*)&As[wm + i * 16 + lr][lq * 8];
        for (int j = 0; j < 4; ++j) bf[j] = *(const bf16x8*)&Bs[wn + j * 16 + lr][lq * 8];
        for (int i = 0; i < 4; ++i)
            for (int j = 0; j < 4; ++j)
                acc[i][j] = __builtin_amdgcn_mfma_f32_16x16x32_bf16(bf[j], af[i], acc[i][j], 0, 0, 0);
    }

    float4 bv4[4] = {{0.f,0.f,0.f,0.f},{0.f,0.f,0.f,0.f},{0.f,0.f,0.f,0.f},{0.f,0.f,0.f,0.f}};
    if (bias)
        for (int j = 0; j < 4; ++j)
            bv4[j] = *(const float4*)&bias[n0 + wn + j * 16 + lq * 4];
    for (int i = 0; i < 4; ++i) {
        const int row = m0 + wm + i * 16 + lr;
        for (int j = 0; j < 4; ++j) {
            const int col = n0 + wn + j * 16 + lq * 4;
            if constexpr (sizeof(TC) == 2) {
                bf16x4 ob;
                ob[0] = (__bf16)(acc[i][j][0] + bv4[j].x);
                ob[1] = (__bf16)(acc[i][j][1] + bv4[j].y);
                ob[2] = (__bf16)(acc[i][j][2] + bv4[j].z);
                ob[3] = (__bf16)(acc[i][j][3] + bv4[j].w);
                *(bf16x4*)&C[(size_t)row * ldc + col] = ob;
            } else {
                float4 ov;
                ov.x = acc[i][j][0] + bv4[j].x;
                ov.y = acc[i][j][1] + bv4[j].y;
                ov.z = acc[i][j][2] + bv4[j].z;
                ov.w = acc[i][j][3] + bv4[j].w;
                *(float4*)&C[(size_t)row * ldc + col] = ov;
            }
        }
    }
}

// ---------------- flash attention v7: BM=256, 8 waves x 32 Q rows, 4 waves/SIMD --------------
// v6 softmax (Q pre-scaled, l via mfma(ones)) kept. Occupancy fix without staging duplication:
// same 512 blocks / same BM=256 tile / same per-block K,V staging traffic, but 512 threads
// (8 waves) per block -> 16 waves/CU = 4 waves/SIMD to cover MFMA->exp2->cvt->MFMA latency.
// Staging duty split: waves 0-3 stage V (round-0 4x4 transpose mapping), waves 4-7 stage K.
__global__ __launch_bounds__(512, 4) void attn_kernel(__bf16* __restrict__ qkv)
{
    __shared__ __bf16 Ks[2][64][72];   // [buf][j][d], padded
    __shared__ __bf16 Vt[2][64][72];   // [buf][d][j' packed], padded

    const int tid = threadIdx.x;
    const int wave = tid >> 6, lane = tid & 63;
    const int lr = lane & 15, lq = lane >> 4;

    const int bid = blockIdx.x;          // 512 blocks: 64 bh x 8 qt
    const int xcd = bid & 7, slot = bid >> 3;
    const int bh = xcd * 8 + (slot >> 3);
    const int qt = slot & 7;
    const int b = bh >> 4, h = bh & 15;
    const int rowbase = b * 2048;
    const int q0 = qt * 256;
    const float c1 = 0.125f * LOG2E;

    // Q fragments (B-operand layout: n=lr -> Q row, k=lq*8 -> d chunk); wave owns 32 rows.
    // Pre-scaled by c1 so QK^T output is already the exp2 argument.
    bf16x8 qf[2][2];
    for (int mt = 0; mt < 2; ++mt)
        for (int ks = 0; ks < 2; ++ks) {
            bf16x8 v = *(const bf16x8*)(qkv +
                (size_t)(rowbase + q0 + wave * 32 + mt * 16 + lr) * 3072 + h * 64 + ks * 32 + lq * 8);
            bf16x8 w;
            for (int e = 0; e < 8; ++e) w[e] = (__bf16)((float)v[e] * c1);
            qf[mt][ks] = w;
        }

    bf16x8 ones8;
    for (int e = 0; e < 8; ++e) ones8[e] = (__bf16)1.0f;

    f32x4 l_acc[2] = {};               // l replicated across rows; col=lr = q row
    f32x4 o_acc[2][4] = {};            // [mt][dt], O^T C-layout: col=lr=i, row=(lq,reg)=d

    // staging duty split over the 256 threads of each half
    const int tid2 = tid & 255;
    const int kr = tid2 >> 2, kc = (tid2 & 3) * 16;    // K: 32B of one row (waves 4-7)
    const int g0 = tid2 & 15;
    const int vj0 = g0 * 4, vd0 = (tid2 >> 4) * 4;     // V: 4x4 register transpose (waves 0-3)
    const int vcol = ((g0 >> 3) * 32) + ((g0 & 3) * 8) + (((g0 >> 2) & 1) * 4);
    const __bf16* kbase = qkv + (size_t)(rowbase + kr) * 3072 + 1024 + h * 64 + kc;
    const __bf16* vbase = qkv + (size_t)(rowbase + vj0) * 3072 + 2048 + h * 64 + vd0;

    bf16x8 ka, kb;
    uint2 t0, t1, t2, t3;

    // tile 0 -> regs -> buf 0
    if (wave >= 4) {
        ka = ((const bf16x8*)kbase)[0];
        kb = ((const bf16x8*)kbase)[1];
        *(bf16x8*)&Ks[0][kr][kc] = ka;
        *(bf16x8*)(&Ks[0][kr][kc] + 8) = kb;
    } else {
        t0 = *(const uint2*)(vbase);
        t1 = *(const uint2*)(vbase + 3072);
        t2 = *(const uint2*)(vbase + 6144);
        t3 = *(const uint2*)(vbase + 9216);
        uint2 c0 = { (t0.x & 0xffffu) | (t1.x << 16), (t2.x & 0xffffu) | (t3.x << 16) };
        uint2 d1 = { (t0.x >> 16) | (t1.x & 0xffff0000u), (t2.x >> 16) | (t3.x & 0xffff0000u) };
        uint2 c2 = { (t0.y & 0xffffu) | (t1.y << 16), (t2.y & 0xffffu) | (t3.y << 16) };
        uint2 d3 = { (t0.y >> 16) | (t1.y & 0xffff0000u), (t2.y >> 16) | (t3.y & 0xffff0000u) };
        *(uint2*)&Vt[0][vd0 + 0][vcol] = c0;
        *(uint2*)&Vt[0][vd0 + 1][vcol] = d1;
        *(uint2*)&Vt[0][vd0 + 2][vcol] = c2;
        *(uint2*)&Vt[0][vd0 + 3][vcol] = d3;
    }

    for (int it = 0; it < 32; ++it) {
        const int cur = it & 1;
        __syncthreads();   // RAW: buf cur visible; WAR: everyone done with buf cur^1

        if (it + 1 < 32) {   // issue next tile's global loads; land during compute
            if (wave >= 4) {
                const __bf16* kg = kbase + (size_t)(it + 1) * 64 * 3072;
                ka = ((const bf16x8*)kg)[0];
                kb = ((const bf16x8*)kg)[1];
            } else {
                const __bf16* vg = vbase + (size_t)(it + 1) * 64 * 3072;
                t0 = *(const uint2*)(vg);
                t1 = *(const uint2*)(vg + 3072);
                t2 = *(const uint2*)(vg + 6144);
                t3 = *(const uint2*)(vg + 9216);
            }
        }

        for (int pi = 0; pi < 2; ++pi) {
            // --- S^T: j in [pi*32, pi*32+32), all 32 Q rows of this wave ---
            f32x4 s[2][2] = {};
            for (int ks = 0; ks < 2; ++ks) {
                bf16x8 kf0 = *(const bf16x8*)&Ks[cur][(2 * pi + 0) * 16 + lr][ks * 32 + lq * 8];
                bf16x8 kf1 = *(const bf16x8*)&Ks[cur][(2 * pi + 1) * 16 + lr][ks * 32 + lq * 8];
                for (int mt = 0; mt < 2; ++mt) {
                    s[mt][0] = __builtin_amdgcn_mfma_f32_16x16x32_bf16(kf0, qf[mt][ks], s[mt][0], 0, 0, 0);
                    s[mt][1] = __builtin_amdgcn_mfma_f32_16x16x32_bf16(kf1, qf[mt][ks], s[mt][1], 0, 0, 0);
                }
            }
            // --- softmax numerator -> packed B-fragment directly (exp2 on raw s) ---
            bf16x8 pfrag[2];
            for (int mt = 0; mt < 2; ++mt) {
                for (int t = 0; t < 2; ++t)
                    for (int r = 0; r < 4; ++r) {
                        float p = __builtin_amdgcn_exp2f(s[mt][t][r]);
                        pfrag[mt][t * 4 + r] = (__bf16)p;
                    }
            }
            // --- l += ones^T P via MFMA ---
            for (int mt = 0; mt < 2; ++mt)
                l_acc[mt] = __builtin_amdgcn_mfma_f32_16x16x32_bf16(ones8, pfrag[mt], l_acc[mt], 0, 0, 0);
            // --- O^T += V^T P (V-fragment = one b128 read, reused across 2 mt) ---
            for (int dt = 0; dt < 4; ++dt) {
                bf16x8 vf = *(const bf16x8*)&Vt[cur][dt * 16 + lr][pi * 32 + lq * 8];
                for (int mt = 0; mt < 2; ++mt)
                    o_acc[mt][dt] = __builtin_amdgcn_mfma_f32_16x16x32_bf16(vf, pfrag[mt], o_acc[mt][dt], 0, 0, 0);
            }
        }

        // --- stage next tile into the other buffer (no barrier needed here) ---
        if (it + 1 < 32) {
            const int nb = cur ^ 1;
            if (wave >= 4) {
                *(bf16x8*)&Ks[nb][kr][kc] = ka;
                *(bf16x8*)(&Ks[nb][kr][kc] + 8) = kb;
            } else {
                uint2 c0 = { (t0.x & 0xffffu) | (t1.x << 16), (t2.x & 0xffffu) | (t3.x << 16) };
                uint2 d1 = { (t0.x >> 16) | (t1.x & 0xffff0000u), (t2.x >> 16) | (t3.x & 0xffff0000u) };
                uint2 c2 = { (t0.y & 0xffffu) | (t1.y << 16), (t2.y & 0xffffu) | (t3.y << 16) };
                uint2 d3 = { (t0.y >> 16) | (t1.y & 0xffff0000u), (t2.y >> 16) | (t3.y & 0xffff0000u) };
                *(uint2*)&Vt[nb][vd0 + 0][vcol] = c0;
                *(uint2*)&Vt[nb][vd0 + 1][vcol] = d1;
                *(uint2*)&Vt[nb][vd0 + 2][vcol] = c2;
                *(uint2*)&Vt[nb][vd0 + 3][vcol] = d3;
            }
        }
    }

    // --- epilogue: l already replicated across rows (col=lr matches o_acc), no shfl ---
    for (int mt = 0; mt < 2; ++mt) {
        float inv = 1.f / l_acc[mt][0];
        for (int dt = 0; dt < 4; ++dt) {
            bf16x4 ob;
            for (int r = 0; r < 4; ++r) ob[r] = (__bf16)(o_acc[mt][dt][r] * inv);
            *(bf16x4*)(qkv + (size_t)(rowbase + q0 + wave * 32 + mt * 16 + lr) * 3072 +
                       h * 64 + dt * 16 + lq * 4) = ob;
        }
    }
}

extern "C" void kernel_launch(void* const* d_in, const int* in_sizes, int n_in,
                              void* d_out, int out_size, void* d_ws, size_t ws_size,
                              hipStream_t stream) {
    const float* x     = (const float*)d_in[0];   // [8192, 1024] fp32
    const float* Wqkv  = (const float*)d_in[1];   // [3072, 1024] fp32
    const float* Wproj = (const float*)d_in[2];   // [1024, 1024] fp32
    const float* bproj = (const float*)d_in[3];   // [1024] fp32
    float* out   = (float*)d_out;                 // [8192, 1024] fp32
    __bf16* qkvb = (__bf16*)d_ws;                 // [8192, 3072] bf16

    const size_t QKV_E = (size_t)8192 * 3072;
    const size_t X_E   = (size_t)8192 * 1024;
    const size_t WQ_E  = (size_t)3072 * 1024;
    const size_t WP_E  = (size_t)1024 * 1024;
    const bool fast = ws_size >= (QKV_E + X_E + WQ_E + WP_E) * sizeof(__bf16);

    if (fast) {
        __bf16* xb  = qkvb + QKV_E;
        __bf16* wqb = xb + X_E;
        __bf16* wpb = wqb + WQ_E;
        cvt_f32_bf16<<<dim3((unsigned)(X_E / 2048)),  256, 0, stream>>>(x, xb);
        cvt_f32_bf16<<<dim3((unsigned)(WQ_E / 2048)), 256, 0, stream>>>(Wqkv, wqb);
        cvt_f32_bf16<<<dim3((unsigned)(WP_E / 2048)), 256, 0, stream>>>(Wproj, wpb);
        gemm_bt_bf16<__bf16><<<dim3(24, 64), 256, 0, stream>>>(
            xb, wqb, nullptr, qkvb, 8192, 3072, 1024, 1024, 1024, 3072);
        attn_kernel<<<dim3(512), 512, 0, stream>>>(qkvb);
        gemm_bt_bf16<float><<<dim3(8, 64), 256, 0, stream>>>(
            qkvb, wpb, bproj, out, 8192, 1024, 1024, 3072, 1024, 1024);
    } else {
        gemm_bt<float, float, __bf16><<<dim3(24, 64), 256, 0, stream>>>(
            x, Wqkv, nullptr, qkvb, 8192, 3072, 1024, 1024, 1024, 3072);
        attn_kernel<<<dim3(512), 512, 0, stream>>>(qkvb);
        gemm_bt<__bf16, float, float><<<dim3(8, 64), 256, 0, stream>>>(
            qkvb, Wproj, bproj, out, 8192, 1024, 1024, 3072, 1024, 1024);
    }
}

// Round 5
// 266.343 us; speedup vs baseline: 1.0403x; 1.0403x over previous
//
#include <hip/hip_runtime.h>
#include <hip/hip_bf16.h>
#include <stdint.h>

typedef __bf16 bf16x4 __attribute__((ext_vector_type(4)));
typedef __bf16 bf16x8 __attribute__((ext_vector_type(8)));
typedef float  f32x4  __attribute__((ext_vector_type(4)));

#define LOG2E 1.44269504088896f

__device__ __forceinline__ void gl2lds16(const __bf16* g, __bf16* l) {
    __builtin_amdgcn_global_load_lds(
        (const __attribute__((address_space(1))) void*)g,
        (__attribute__((address_space(3))) void*)l, 16, 0, 0);
}

// ---------------- fused fp32 -> bf16 for all three tensors (one launch) ----------------------
// blocks [0,4096): x, [4096,5632): Wqkv, [5632,6144): Wproj. Each block converts 2048 elems.
__global__ __launch_bounds__(256) void cvt3_f32_bf16(
    const float* __restrict__ x,  __bf16* __restrict__ xb,
    const float* __restrict__ wq, __bf16* __restrict__ wqb,
    const float* __restrict__ wp, __bf16* __restrict__ wpb) {
    const int bid = blockIdx.x;
    const float* in; __bf16* out; int base;
    if (bid < 4096)      { in = x;  out = xb;  base = bid; }
    else if (bid < 5632) { in = wq; out = wqb; base = bid - 4096; }
    else                 { in = wp; out = wpb; base = bid - 5632; }
    size_t i = ((size_t)base * 256 + threadIdx.x) * 8;
    float4 a = ((const float4*)(in + i))[0];
    float4 b = ((const float4*)(in + i))[1];
    bf16x8 v;
    v[0] = (__bf16)a.x; v[1] = (__bf16)a.y; v[2] = (__bf16)a.z; v[3] = (__bf16)a.w;
    v[4] = (__bf16)b.x; v[5] = (__bf16)b.y; v[6] = (__bf16)b.z; v[7] = (__bf16)b.w;
    *(bf16x8*)(out + i) = v;
}

// ---------------- all-bf16 GEMM, m97 structure, 128x128 tile ---------------------------------
// Default block->tile mapping (round-robin across XCDs keeps each XCD's B-slice L2-resident;
// chunked XCD swizzle measured -10us in round 4 -- B working set per m-row exceeds 4MB L2).
// Epilogue: MFMA operands swapped (bf first) so D's (lq,reg) axis = N -> 16 vector stores.
template<typename TC>
__global__ __launch_bounds__(256) void gemm_bt_bf16(
    const __bf16* __restrict__ A, const __bf16* __restrict__ B,
    const float* __restrict__ bias, TC* __restrict__ C,
    int M, int N, int K, int lda, int ldb, int ldc)
{
    __shared__ __bf16 As[128][32];
    __shared__ __bf16 Bs[128][32];
    const int tid = threadIdx.x;
    const int wave = tid >> 6, lane = tid & 63;
    const int lr = lane & 15, lq = lane >> 4;
    const int m0 = blockIdx.y * 128, n0 = blockIdx.x * 128;
    const int wm = (wave >> 1) * 64, wn = (wave & 1) * 64;

    f32x4 acc[4][4] = {};

    const int sr = lane >> 2;
    const int sc = (lane & 3) * 8;
    const __bf16* ag[2]; const __bf16* bg[2];
    __bf16* alds[2]; __bf16* blds[2];
    for (int t = 0; t < 2; ++t) {
        int chunk = wave * 2 + t;
        ag[t] = A + (size_t)(m0 + chunk * 16 + sr) * lda + sc;
        bg[t] = B + (size_t)(n0 + chunk * 16 + sr) * ldb + sc;
        alds[t] = &As[0][0] + chunk * 512;
        blds[t] = &Bs[0][0] + chunk * 512;
    }

    for (int k0 = 0; k0 < K; k0 += 32) {
        __syncthreads();
        gl2lds16(ag[0] + k0, alds[0]);
        gl2lds16(ag[1] + k0, alds[1]);
        gl2lds16(bg[0] + k0, blds[0]);
        gl2lds16(bg[1] + k0, blds[1]);
        __syncthreads();
        bf16x8 af[4], bf[4];
        for (int i = 0; i < 4; ++i) af[i] = *(const bf16x8*)&As[wm + i * 16 + lr][lq * 8];
        for (int j = 0; j < 4; ++j) bf[j] = *(const bf16x8*)&Bs[wn + j * 16 + lr][lq * 8];
        for (int i = 0; i < 4; ++i)
            for (int j = 0; j < 4; ++j)
                acc[i][j] = __builtin_amdgcn_mfma_f32_16x16x32_bf16(bf[j], af[i], acc[i][j], 0, 0, 0);
    }

    // epilogue: D row axis (lq,reg) = N (4 consecutive cols), D col axis (lr) = M row
    float4 bv4[4] = {{0.f,0.f,0.f,0.f},{0.f,0.f,0.f,0.f},{0.f,0.f,0.f,0.f},{0.f,0.f,0.f,0.f}};
    if (bias)
        for (int j = 0; j < 4; ++j)
            bv4[j] = *(const float4*)&bias[n0 + wn + j * 16 + lq * 4];
    for (int i = 0; i < 4; ++i) {
        const int row = m0 + wm + i * 16 + lr;
        for (int j = 0; j < 4; ++j) {
            const int col = n0 + wn + j * 16 + lq * 4;
            if constexpr (sizeof(TC) == 2) {
                bf16x4 ob;
                ob[0] = (__bf16)(acc[i][j][0] + bv4[j].x);
                ob[1] = (__bf16)(acc[i][j][1] + bv4[j].y);
                ob[2] = (__bf16)(acc[i][j][2] + bv4[j].z);
                ob[3] = (__bf16)(acc[i][j][3] + bv4[j].w);
                *(bf16x4*)&C[(size_t)row * ldc + col] = ob;
            } else {
                float4 ov;
                ov.x = acc[i][j][0] + bv4[j].x;
                ov.y = acc[i][j][1] + bv4[j].y;
                ov.z = acc[i][j][2] + bv4[j].z;
                ov.w = acc[i][j][3] + bv4[j].w;
                *(float4*)&C[(size_t)row * ldc + col] = ov;
            }
        }
    }
}

// ---------------- fallback GEMM: fp32 ingest, stage16 cvt ------------------------------------
__device__ __forceinline__ void stage16(const float* __restrict__ g, __bf16* l) {
    float4 a = ((const float4*)g)[0];
    float4 b = ((const float4*)g)[1];
    float4 c = ((const float4*)g)[2];
    float4 d = ((const float4*)g)[3];
    bf16x8 lo, hi;
    lo[0] = (__bf16)a.x; lo[1] = (__bf16)a.y; lo[2] = (__bf16)a.z; lo[3] = (__bf16)a.w;
    lo[4] = (__bf16)b.x; lo[5] = (__bf16)b.y; lo[6] = (__bf16)b.z; lo[7] = (__bf16)b.w;
    hi[0] = (__bf16)c.x; hi[1] = (__bf16)c.y; hi[2] = (__bf16)c.z; hi[3] = (__bf16)c.w;
    hi[4] = (__bf16)d.x; hi[5] = (__bf16)d.y; hi[6] = (__bf16)d.z; hi[7] = (__bf16)d.w;
    ((bf16x8*)l)[0] = lo;
    ((bf16x8*)l)[1] = hi;
}
__device__ __forceinline__ void stage16(const __bf16* __restrict__ g, __bf16* l) {
    ((bf16x8*)l)[0] = ((const bf16x8*)g)[0];
    ((bf16x8*)l)[1] = ((const bf16x8*)g)[1];
}

template<typename TA, typename TB, typename TC>
__global__ __launch_bounds__(256) void gemm_bt(
    const TA* __restrict__ A, const TB* __restrict__ B,
    const float* __restrict__ bias, TC* __restrict__ C,
    int M, int N, int K, int lda, int ldb, int ldc)
{
    __shared__ __bf16 As[128][40];
    __shared__ __bf16 Bs[128][40];
    const int tid = threadIdx.x;
    const int wave = tid >> 6, lane = tid & 63;
    const int lr = lane & 15, lq = lane >> 4;
    const int m0 = blockIdx.y * 128, n0 = blockIdx.x * 128;
    const int wm = (wave >> 1) * 64, wn = (wave & 1) * 64;
    const int srow = tid >> 1, scol = (tid & 1) * 16;

    f32x4 acc[4][4] = {};
    const TA* agp = A + (size_t)(m0 + srow) * lda + scol;
    const TB* bgp = B + (size_t)(n0 + srow) * ldb + scol;

    for (int k0 = 0; k0 < K; k0 += 32) {
        __syncthreads();
        stage16(agp + k0, &As[srow][scol]);
        stage16(bgp + k0, &Bs[srow][scol]);
        __syncthreads();
        bf16x8 af[4], bf[4];
        for (int i = 0; i < 4; ++i) af[i] = *(const bf16x8*)&As[wm + i * 16 + lr][lq * 8];
        for (int j = 0; j < 4; ++j) bf[j] = *(const bf16x8*)&Bs[wn + j * 16 + lr][lq * 8];
        for (int i = 0; i < 4; ++i)
            for (int j = 0; j < 4; ++j)
                acc[i][j] = __builtin_amdgcn_mfma_f32_16x16x32_bf16(bf[j], af[i], acc[i][j], 0, 0, 0);
    }

    float4 bv4[4] = {{0.f,0.f,0.f,0.f},{0.f,0.f,0.f,0.f},{0.f,0.f,0.f,0.f},{0.f,0.f,0.f,0.f}};
    if (bias)
        for (int j = 0; j < 4; ++j)
            bv4[j] = *(const float4*)&bias[n0 + wn + j * 16 + lq * 4];
    for (int i = 0; i < 4; ++i) {
        const int row = m0 + wm + i * 16 + lr;
        for (int j = 0; j < 4; ++j) {
            const int col = n0 + wn + j * 16 + lq * 4;
            if constexpr (sizeof(TC) == 2) {
                bf16x4 ob;
                ob[0] = (__bf16)(acc[i][j][0] + bv4[j].x);
                ob[1] = (__bf16)(acc[i][j][1] + bv4[j].y);
                ob[2] = (__bf16)(acc[i][j][2] + bv4[j].z);
                ob[3] = (__bf16)(acc[i][j][3] + bv4[j].w);
                *(bf16x4*)&C[(size_t)row * ldc + col] = ob;
            } else {
                float4 ov;
                ov.x = acc[i][j][0] + bv4[j].x;
                ov.y = acc[i][j][1] + bv4[j].y;
                ov.z = acc[i][j][2] + bv4[j].z;
                ov.w = acc[i][j][3] + bv4[j].w;
                *(float4*)&C[(size_t)row * ldc + col] = ov;
            }
        }
    }
}

// ---------------- flash attention v7: BM=256, 8 waves x 32 Q rows, 4 waves/SIMD --------------
// v6 softmax (Q pre-scaled, l via mfma(ones)) kept. Occupancy fix without staging duplication:
// same 512 blocks / same BM=256 tile / same per-block K,V staging traffic, but 512 threads
// (8 waves) per block -> 16 waves/CU = 4 waves/SIMD to cover MFMA->exp2->cvt->MFMA latency.
// Staging duty split: waves 0-3 stage V (round-0 4x4 transpose mapping), waves 4-7 stage K.
__global__ __launch_bounds__(512, 4) void attn_kernel(__bf16* __restrict__ qkv)
{
    __shared__ __bf16 Ks[2][64][72];   // [buf][j][d], padded
    __shared__ __bf16 Vt[2][64][72];   // [buf][d][j' packed], padded

    const int tid = threadIdx.x;
    const int wave = tid >> 6, lane = tid & 63;
    const int lr = lane & 15, lq = lane >> 4;

    const int bid = blockIdx.x;          // 512 blocks: 64 bh x 8 qt
    const int xcd = bid & 7, slot = bid >> 3;
    const int bh = xcd * 8 + (slot >> 3);
    const int qt = slot & 7;
    const int b = bh >> 4, h = bh & 15;
    const int rowbase = b * 2048;
    const int q0 = qt * 256;
    const float c1 = 0.125f * LOG2E;

    // Q fragments (B-operand layout: n=lr -> Q row, k=lq*8 -> d chunk); wave owns 32 rows.
    // Pre-scaled by c1 so QK^T output is already the exp2 argument.
    bf16x8 qf[2][2];
    for (int mt = 0; mt < 2; ++mt)
        for (int ks = 0; ks < 2; ++ks) {
            bf16x8 v = *(const bf16x8*)(qkv +
                (size_t)(rowbase + q0 + wave * 32 + mt * 16 + lr) * 3072 + h * 64 + ks * 32 + lq * 8);
            bf16x8 w;
            for (int e = 0; e < 8; ++e) w[e] = (__bf16)((float)v[e] * c1);
            qf[mt][ks] = w;
        }

    bf16x8 ones8;
    for (int e = 0; e < 8; ++e) ones8[e] = (__bf16)1.0f;

    f32x4 l_acc[2] = {};               // l replicated across rows; col=lr = q row
    f32x4 o_acc[2][4] = {};            // [mt][dt], O^T C-layout: col=lr=i, row=(lq,reg)=d

    // staging duty split over the 256 threads of each half
    const int tid2 = tid & 255;
    const int kr = tid2 >> 2, kc = (tid2 & 3) * 16;    // K: 32B of one row (waves 4-7)
    const int g0 = tid2 & 15;
    const int vj0 = g0 * 4, vd0 = (tid2 >> 4) * 4;     // V: 4x4 register transpose (waves 0-3)
    const int vcol = ((g0 >> 3) * 32) + ((g0 & 3) * 8) + (((g0 >> 2) & 1) * 4);
    const __bf16* kbase = qkv + (size_t)(rowbase + kr) * 3072 + 1024 + h * 64 + kc;
    const __bf16* vbase = qkv + (size_t)(rowbase + vj0) * 3072 + 2048 + h * 64 + vd0;

    bf16x8 ka, kb;
    uint2 t0, t1, t2, t3;

    // tile 0 -> regs -> buf 0
    if (wave >= 4) {
        ka = ((const bf16x8*)kbase)[0];
        kb = ((const bf16x8*)kbase)[1];
        *(bf16x8*)&Ks[0][kr][kc] = ka;
        *(bf16x8*)(&Ks[0][kr][kc] + 8) = kb;
    } else {
        t0 = *(const uint2*)(vbase);
        t1 = *(const uint2*)(vbase + 3072);
        t2 = *(const uint2*)(vbase + 6144);
        t3 = *(const uint2*)(vbase + 9216);
        uint2 c0 = { (t0.x & 0xffffu) | (t1.x << 16), (t2.x & 0xffffu) | (t3.x << 16) };
        uint2 d1 = { (t0.x >> 16) | (t1.x & 0xffff0000u), (t2.x >> 16) | (t3.x & 0xffff0000u) };
        uint2 c2 = { (t0.y & 0xffffu) | (t1.y << 16), (t2.y & 0xffffu) | (t3.y << 16) };
        uint2 d3 = { (t0.y >> 16) | (t1.y & 0xffff0000u), (t2.y >> 16) | (t3.y & 0xffff0000u) };
        *(uint2*)&Vt[0][vd0 + 0][vcol] = c0;
        *(uint2*)&Vt[0][vd0 + 1][vcol] = d1;
        *(uint2*)&Vt[0][vd0 + 2][vcol] = c2;
        *(uint2*)&Vt[0][vd0 + 3][vcol] = d3;
    }

    for (int it = 0; it < 32; ++it) {
        const int cur = it & 1;
        __syncthreads();   // RAW: buf cur visible; WAR: everyone done with buf cur^1

        if (it + 1 < 32) {   // issue next tile's global loads; land during compute
            if (wave >= 4) {
                const __bf16* kg = kbase + (size_t)(it + 1) * 64 * 3072;
                ka = ((const bf16x8*)kg)[0];
                kb = ((const bf16x8*)kg)[1];
            } else {
                const __bf16* vg = vbase + (size_t)(it + 1) * 64 * 3072;
                t0 = *(const uint2*)(vg);
                t1 = *(const uint2*)(vg + 3072);
                t2 = *(const uint2*)(vg + 6144);
                t3 = *(const uint2*)(vg + 9216);
            }
        }

        for (int pi = 0; pi < 2; ++pi) {
            // --- S^T: j in [pi*32, pi*32+32), all 32 Q rows of this wave ---
            f32x4 s[2][2] = {};
            for (int ks = 0; ks < 2; ++ks) {
                bf16x8 kf0 = *(const bf16x8*)&Ks[cur][(2 * pi + 0) * 16 + lr][ks * 32 + lq * 8];
                bf16x8 kf1 = *(const bf16x8*)&Ks[cur][(2 * pi + 1) * 16 + lr][ks * 32 + lq * 8];
                for (int mt = 0; mt < 2; ++mt) {
                    s[mt][0] = __builtin_amdgcn_mfma_f32_16x16x32_bf16(kf0, qf[mt][ks], s[mt][0], 0, 0, 0);
                    s[mt][1] = __builtin_amdgcn_mfma_f32_16x16x32_bf16(kf1, qf[mt][ks], s[mt][1], 0, 0, 0);
                }
            }
            // --- softmax numerator -> packed B-fragment directly (exp2 on raw s) ---
            bf16x8 pfrag[2];
            for (int mt = 0; mt < 2; ++mt) {
                for (int t = 0; t < 2; ++t)
                    for (int r = 0; r < 4; ++r) {
                        float p = __builtin_amdgcn_exp2f(s[mt][t][r]);
                        pfrag[mt][t * 4 + r] = (__bf16)p;
                    }
            }
            // --- l += ones^T P via MFMA ---
            for (int mt = 0; mt < 2; ++mt)
                l_acc[mt] = __builtin_amdgcn_mfma_f32_16x16x32_bf16(ones8, pfrag[mt], l_acc[mt], 0, 0, 0);
            // --- O^T += V^T P (V-fragment = one b128 read, reused across 2 mt) ---
            for (int dt = 0; dt < 4; ++dt) {
                bf16x8 vf = *(const bf16x8*)&Vt[cur][dt * 16 + lr][pi * 32 + lq * 8];
                for (int mt = 0; mt < 2; ++mt)
                    o_acc[mt][dt] = __builtin_amdgcn_mfma_f32_16x16x32_bf16(vf, pfrag[mt], o_acc[mt][dt], 0, 0, 0);
            }
        }

        // --- stage next tile into the other buffer (no barrier needed here) ---
        if (it + 1 < 32) {
            const int nb = cur ^ 1;
            if (wave >= 4) {
                *(bf16x8*)&Ks[nb][kr][kc] = ka;
                *(bf16x8*)(&Ks[nb][kr][kc] + 8) = kb;
            } else {
                uint2 c0 = { (t0.x & 0xffffu) | (t1.x << 16), (t2.x & 0xffffu) | (t3.x << 16) };
                uint2 d1 = { (t0.x >> 16) | (t1.x & 0xffff0000u), (t2.x >> 16) | (t3.x & 0xffff0000u) };
                uint2 c2 = { (t0.y & 0xffffu) | (t1.y << 16), (t2.y & 0xffffu) | (t3.y << 16) };
                uint2 d3 = { (t0.y >> 16) | (t1.y & 0xffff0000u), (t2.y >> 16) | (t3.y & 0xffff0000u) };
                *(uint2*)&Vt[nb][vd0 + 0][vcol] = c0;
                *(uint2*)&Vt[nb][vd0 + 1][vcol] = d1;
                *(uint2*)&Vt[nb][vd0 + 2][vcol] = c2;
                *(uint2*)&Vt[nb][vd0 + 3][vcol] = d3;
            }
        }
    }

    // --- epilogue: l already replicated across rows (col=lr matches o_acc), no shfl ---
    for (int mt = 0; mt < 2; ++mt) {
        float inv = 1.f / l_acc[mt][0];
        for (int dt = 0; dt < 4; ++dt) {
            bf16x4 ob;
            for (int r = 0; r < 4; ++r) ob[r] = (__bf16)(o_acc[mt][dt][r] * inv);
            *(bf16x4*)(qkv + (size_t)(rowbase + q0 + wave * 32 + mt * 16 + lr) * 3072 +
                       h * 64 + dt * 16 + lq * 4) = ob;
        }
    }
}

extern "C" void kernel_launch(void* const* d_in, const int* in_sizes, int n_in,
                              void* d_out, int out_size, void* d_ws, size_t ws_size,
                              hipStream_t stream) {
    const float* x     = (const float*)d_in[0];   // [8192, 1024] fp32
    const float* Wqkv  = (const float*)d_in[1];   // [3072, 1024] fp32
    const float* Wproj = (const float*)d_in[2];   // [1024, 1024] fp32
    const float* bproj = (const float*)d_in[3];   // [1024] fp32
    float* out   = (float*)d_out;                 // [8192, 1024] fp32
    __bf16* qkvb = (__bf16*)d_ws;                 // [8192, 3072] bf16

    const size_t QKV_E = (size_t)8192 * 3072;
    const size_t X_E   = (size_t)8192 * 1024;
    const size_t WQ_E  = (size_t)3072 * 1024;
    const size_t WP_E  = (size_t)1024 * 1024;
    const bool fast = ws_size >= (QKV_E + X_E + WQ_E + WP_E) * sizeof(__bf16);

    if (fast) {
        __bf16* xb  = qkvb + QKV_E;
        __bf16* wqb = xb + X_E;
        __bf16* wpb = wqb + WQ_E;
        cvt3_f32_bf16<<<dim3(6144), 256, 0, stream>>>(x, xb, Wqkv, wqb, Wproj, wpb);
        gemm_bt_bf16<__bf16><<<dim3(24, 64), 256, 0, stream>>>(
            xb, wqb, nullptr, qkvb, 8192, 3072, 1024, 1024, 1024, 3072);
        attn_kernel<<<dim3(512), 512, 0, stream>>>(qkvb);
        gemm_bt_bf16<float><<<dim3(8, 64), 256, 0, stream>>>(
            qkvb, wpb, bproj, out, 8192, 1024, 1024, 3072, 1024, 1024);
    } else {
        gemm_bt<float, float, __bf16><<<dim3(24, 64), 256, 0, stream>>>(
            x, Wqkv, nullptr, qkvb, 8192, 3072, 1024, 1024, 1024, 3072);
        attn_kernel<<<dim3(512), 512, 0, stream>>>(qkvb);
        gemm_bt<__bf16, float, float><<<dim3(8, 64), 256, 0, stream>>>(
            qkvb, Wproj, bproj, out, 8192, 1024, 1024, 3072, 1024, 1024);
    }
}